// Round 17
// baseline (103.562 us; speedup 1.0000x reference)
//
#include <hip/hip_runtime.h>
#include <hip/hip_bf16.h>

typedef unsigned short u16;
typedef __attribute__((ext_vector_type(8))) short bf16x8;
typedef __attribute__((ext_vector_type(4))) float f32x4;
typedef __attribute__((ext_vector_type(16))) float f32x16;
typedef __attribute__((ext_vector_type(4))) unsigned u32x4;

#define MFMA(a, b, c) __builtin_amdgcn_mfma_f32_16x16x32_bf16(a, b, c, 0, 0, 0)
#define MFMA32(a, b, c) __builtin_amdgcn_mfma_f32_32x32x16_bf16(a, b, c, 0, 0, 0)

#define STAGE16(g, l) __builtin_amdgcn_global_load_lds( \
    (const __attribute__((address_space(1))) void*)(g),  \
    (__attribute__((address_space(3))) void*)(l), 16, 0, 0)

#define EXP2(x) __builtin_amdgcn_exp2f(x)

__device__ __forceinline__ u16 f2bf(float f) {
  union { float f; unsigned u; } v; v.f = f;
  return (u16)((v.u + 0x7fffu + ((v.u >> 16) & 1u)) >> 16);
}

// hardware pack: lo -> D[15:0], hi -> D[31:16], RNE
__device__ __forceinline__ unsigned pack_bf2(float lo, float hi) {
  unsigned r;
  asm("v_cvt_pk_bf16_f32 %0, %1, %2" : "=v"(r) : "v"(lo), "v"(hi));
  return r;
}

// swap upper 32 lanes of a with lower 32 lanes of b
__device__ __forceinline__ void pl32swap(unsigned &a, unsigned &b) {
  asm("v_permlane32_swap_b32 %0, %1" : "+v"(a), "+v"(b));
}

// ---------------------------------------------------------------- convert
__global__ __launch_bounds__(256) void convert_all(
    const float* __restrict__ x, const float* __restrict__ y,
    const float* __restrict__ wq, const float* __restrict__ wk,
    const float* __restrict__ wv, const float* __restrict__ wp,
    u16* __restrict__ xb, u16* __restrict__ yb,
    u16* __restrict__ wqb, u16* __restrict__ wkb,
    u16* __restrict__ wvb, u16* __restrict__ wpb)
{
  constexpr int G0 = 4096 * 768 / 4;
  constexpr int G1 = G0 + 8192 * 768 / 4;
  constexpr int GW = 768 * 768 / 4;
  int g = blockIdx.x * 256 + threadIdx.x;
  const float* s; u16* d; int o;
  if      (g < G0)          { s = x;  d = xb;  o = g; }
  else if (g < G1)          { s = y;  d = yb;  o = g - G0; }
  else if (g < G1 + GW)     { s = wq; d = wqb; o = g - G1; }
  else if (g < G1 + 2*GW)   { s = wk; d = wkb; o = g - G1 - GW; }
  else if (g < G1 + 3*GW)   { s = wv; d = wvb; o = g - G1 - 2*GW; }
  else if (g < G1 + 4*GW)   { s = wp; d = wpb; o = g - G1 - 3*GW; }
  else return;
  float4 v = reinterpret_cast<const float4*>(s)[o];
  ushort4 r;
  r.x = f2bf(v.x); r.y = f2bf(v.y); r.z = f2bf(v.z); r.w = f2bf(v.w);
  reinterpret_cast<ushort4*>(d)[o] = r;
}

// ---------------------------------------------------------------- GEMM
// C = A @ W^T (both K-contiguous). 128x128 tile, BK=64, 4 waves (2x2).
// Double-buffered LDS, depth-1 prefetch, one __syncthreads per iter.
// Epilogue writes MFMA-fragment-linearized layouts:
//   Qa[bh][q>>5][t][h2][q&31][8]   (pre-scaled by SCALE*log2e)
//   Ka[bh][kv>>5][t][h2][kv&31][8]
//   Vw[bh][kv>>3][d][kv&7]
template <bool PROJ>
__global__ __launch_bounds__(256) void gemm_k(
    const u16* __restrict__ A0, const u16* __restrict__ A1,
    const u16* __restrict__ W0, const u16* __restrict__ W1,
    const u16* __restrict__ W2,
    u16* __restrict__ Qa, u16* __restrict__ Ka, u16* __restrict__ Vw,
    const float* __restrict__ bias, float* __restrict__ fout)
{
  __shared__ u16 sA[2][128 * 64];
  __shared__ u16 sB[2][128 * 64];

  // XCD-aware bijective swizzle (grid: PROJ ? 192 : 960; both %8 == 0)
  const int nper = PROJ ? 24 : 120;
  int bid = (blockIdx.x & 7) * nper + (blockIdx.x >> 3);

  const u16 *A, *W;
  int mode, mt, nt;
  if (PROJ)           { mode = 3; A = A0; W = W0; mt = bid / 6;        nt = bid % 6; }
  else if (bid < 192) { mode = 0; A = A0; W = W0; mt = bid / 6;        nt = bid % 6; }
  else if (bid < 576) { mode = 1; A = A1; W = W1; mt = (bid-192) / 6;  nt = (bid-192) % 6; }
  else                { mode = 2; A = A1; W = W2; mt = (bid-576) / 6;  nt = (bid-576) % 6; }

  const int tid = threadIdx.x;
  const int w = tid >> 6, l = tid & 63;
  const int wm = w >> 1, wn = w & 1;
  const int g = l >> 4, m = l & 15;

  const int mbase = mt * 128, nbase = nt * 128;

  const int srow = l >> 3;
  const int schunk = ((l & 7) ^ srow) * 8;
  const u16* Ag = A + (size_t)(mbase + srow) * 768 + schunk;
  const u16* Wg = W + (size_t)(nbase + srow) * 768 + schunk;

  f32x4 acc[4][4] = {};

  // prologue: stage tile 0 into buf 0
#pragma unroll
  for (int i = 0; i < 4; ++i) {
    const int ri = (i * 4 + w) * 8;
    STAGE16(Ag + (size_t)ri * 768, (char*)sA[0] + ri * 128);
    STAGE16(Wg + (size_t)ri * 768, (char*)sB[0] + ri * 128);
  }

  for (int kt = 0; kt < 12; ++kt) {
    __syncthreads();   // tile kt DMA landed; buf^1 readers (kt-1) done

    if (kt < 11) {
      const int ko = (kt + 1) * 64;
      const int nb = (kt + 1) & 1;
#pragma unroll
      for (int i = 0; i < 4; ++i) {
        const int ri = (i * 4 + w) * 8;
        STAGE16(Ag + (size_t)ri * 768 + ko, (char*)sA[nb] + ri * 128);
        STAGE16(Wg + (size_t)ri * 768 + ko, (char*)sB[nb] + ri * 128);
      }
    }

    const int cb = kt & 1;
    bf16x8 af[2][4], bfr[2][4];
#pragma unroll
    for (int c = 0; c < 2; ++c)
#pragma unroll
      for (int t = 0; t < 4; ++t) {
        const int ar = wm * 64 + t * 16 + m;
        const int br = wn * 64 + t * 16 + m;
        const int cp = ((c * 4 + g) ^ (l & 7)) * 16;
        af[c][t]  = *reinterpret_cast<const bf16x8*>((const char*)sA[cb] + ar * 128 + cp);
        bfr[c][t] = *reinterpret_cast<const bf16x8*>((const char*)sB[cb] + br * 128 + cp);
      }
#pragma unroll
    for (int c = 0; c < 2; ++c)
#pragma unroll
      for (int mi = 0; mi < 4; ++mi)
#pragma unroll
        for (int ni = 0; ni < 4; ++ni)
          acc[mi][ni] = MFMA(af[c][mi], bfr[c][ni], acc[mi][ni]);
  }

  const float QSCALE = 0.18033688011112042f;  // 0.125 * log2(e)
  const int rowb = mbase + wm * 64 + g * 4;
  const int colb = nbase + wn * 64 + m;
#pragma unroll
  for (int mi = 0; mi < 4; ++mi) {
#pragma unroll
    for (int ni = 0; ni < 4; ++ni) {
      const int col = colb + ni * 16;
      const int h = col >> 6, d = col & 63;
      const int t_ = d >> 4, hh = (d >> 3) & 1, di = d & 7;
      const int fo = t_ * 512 + hh * 256 + di;     // fragment inner offset
      if constexpr (PROJ) {
#pragma unroll
        for (int r = 0; r < 4; ++r) {
          const int row = rowb + mi * 16 + r;
          fout[(size_t)row * 768 + col] = acc[mi][ni][r] + bias[col];
        }
      } else {
        if (mode == 0) {
#pragma unroll
          for (int r = 0; r < 4; ++r) {
            const int row = rowb + mi * 16 + r;
            const int b_ = row >> 10, n = row & 1023;
            Qa[((size_t)(b_ * 12 + h) * 32 + (n >> 5)) * 2048 + fo + (n & 31) * 8] =
                f2bf(acc[mi][ni][r] * QSCALE);
          }
        } else if (mode == 1) {
#pragma unroll
          for (int r = 0; r < 4; ++r) {
            const int row = rowb + mi * 16 + r;
            const int b_ = row >> 11, n = row & 2047;
            Ka[(size_t)(b_ * 12 + h) * 131072 + (n >> 5) * 2048 + fo + (n & 31) * 8] =
                f2bf(acc[mi][ni][r]);
          }
        } else {
          // Vw[bh][n>>3][d][n&7]; 4 regs = tokens n..n+3 (n % 4 == 0)
          const int row = rowb + mi * 16;
          const int b_ = row >> 11, n = row & 2047;
          ushort4 pk;
          pk.x = f2bf(acc[mi][ni][0]); pk.y = f2bf(acc[mi][ni][1]);
          pk.z = f2bf(acc[mi][ni][2]); pk.w = f2bf(acc[mi][ni][3]);
          *reinterpret_cast<ushort4*>(
              Vw + (size_t)(b_ * 12 + h) * 131072 + (n >> 3) * 512 + d * 8 + (n & 7)) = pk;
        }
      }
    }
  }
}

// ---------------------------------------------------------------- attention
// Barrier-free 32x32x16 flash attention, MANUAL 2-ITER BODY with
// top-hoisted loads (prefetch WITHOUT cross-iteration register rotation).
// Block = 2 INDEPENDENT waves: wave w covers the same 32-q tile over kv
// half w*1024; each body handles kv tiles a (=2*kt2) and b (=2*kt2+1).
// K_a, K_b, V_a are issued at the top of the body: K_b gets the whole
// a-half (~1000cy) of latency cover, V_a the a-softmax (~500cy); V_b is
// issued at the start of half b. Only K_a's latency stays exposed
// (once per 128 kv). No values carried across loop iterations.
// l = R8's proven in-lane add tree + per-iter shfl_xor(32) (frees the
// ones-MFMA's 20 VGPRs to keep peak pressure < the 3-wave/SIMD cap).
// Epilogue = R8's proven cL[2][32] cross-wave combine.
__global__ __launch_bounds__(128, 3) void attn_fwd(
    const u16* __restrict__ Qa, const u16* __restrict__ Ka,
    const u16* __restrict__ Vw, u16* __restrict__ AOb)
{
  __shared__ float cO[32 * 64];
  __shared__ float cL[2][32];

  const int bid = blockIdx.x;
  const int bh = bid % 48, qt = bid / 48;   // 48%8==0 -> head pinned to XCD
  const int tid = threadIdx.x;
  const int w = tid >> 6, l = tid & 63;
  const int h = l >> 5, q = l & 31;

  // Q B-frags (coalesced 16B): lane holds Q[q0+q][16t+8h+i]
  const u16* qb = Qa + (size_t)(bh * 32 + qt) * 2048 + h * 256 + q * 8;
  bf16x8 qf[4];
#pragma unroll
  for (int t = 0; t < 4; ++t)
    qf[t] = *reinterpret_cast<const bf16x8*>(qb + t * 512);

  // K A-frag base / V B-frag base for this wave's kv half
  const u16* kb = Ka + (size_t)bh * 131072 + (size_t)w * 65536 + h * 256 + q * 8;
  const u16* vb = Vw + (size_t)bh * 131072 + (size_t)w * 65536 + h * 512 + q * 8;

  f32x16 o0 = {}, o1 = {};
  float lrun = 0.f;

#pragma unroll 1
  for (int kt2 = 0; kt2 < 8; ++kt2) {
    const u16* kpa = kb + (size_t)kt2 * 8192;   // 2 K-tiles (2x4096 elems)
    const u16* vpa = vb + (size_t)kt2 * 8192;   // 2 V-tiles

    // ---- hoisted loads: K_a, K_b, V_a (K_b/V_a latency hidden under a)
    bf16x8 kfa0[4], kfa1[4], kfb0[4], kfb1[4], vfa0[4], vfa1[4];
#pragma unroll
    for (int t = 0; t < 4; ++t) {
      kfa0[t] = *reinterpret_cast<const bf16x8*>(kpa + t * 512);
      kfa1[t] = *reinterpret_cast<const bf16x8*>(kpa + 2048 + t * 512);
    }
#pragma unroll
    for (int t = 0; t < 4; ++t) {
      kfb0[t] = *reinterpret_cast<const bf16x8*>(kpa + 4096 + t * 512);
      kfb1[t] = *reinterpret_cast<const bf16x8*>(kpa + 6144 + t * 512);
    }
#pragma unroll
    for (int t = 0; t < 4; ++t) {
      vfa0[t] = *reinterpret_cast<const bf16x8*>(vpa + t * 1024);
      vfa1[t] = *reinterpret_cast<const bf16x8*>(vpa + t * 1024 + 256);
    }

    // ================= half a (kv tile 2*kt2) =================
    {
      f32x16 s0 = {}, s1 = {};
      __builtin_amdgcn_s_setprio(1);
#pragma unroll
      for (int t = 0; t < 4; ++t) {
        s0 = MFMA32(kfa0[t], qf[t], s0);
        s1 = MFMA32(kfa1[t], qf[t], s1);
      }
      __builtin_amdgcn_s_setprio(0);

      float p0[16], p1[16];
#pragma unroll
      for (int r = 0; r < 16; ++r) p0[r] = EXP2(s0[r]);
#pragma unroll
      for (int r = 0; r < 16; ++r) p1[r] = EXP2(s1[r]);

      float a8[8];
#pragma unroll
      for (int i = 0; i < 8; ++i)
        a8[i] = (p0[2*i] + p0[2*i+1]) + (p1[2*i] + p1[2*i+1]);
      float ts = ((a8[0]+a8[1]) + (a8[2]+a8[3])) + ((a8[4]+a8[5]) + (a8[6]+a8[7]));
      ts += __shfl_xor(ts, 32);
      lrun += ts;

      unsigned pk[2][4][2];
#pragma unroll
      for (int qd = 0; qd < 4; ++qd) {
        pk[0][qd][0] = pack_bf2(p0[4*qd+0], p0[4*qd+1]);
        pk[0][qd][1] = pack_bf2(p0[4*qd+2], p0[4*qd+3]);
        pk[1][qd][0] = pack_bf2(p1[4*qd+0], p1[4*qd+1]);
        pk[1][qd][1] = pack_bf2(p1[4*qd+2], p1[4*qd+3]);
      }

      __builtin_amdgcn_s_setprio(1);
#pragma unroll
      for (int t = 0; t < 4; ++t) {
        const int c = t >> 1, j0 = 2 * (t & 1);
        unsigned x0 = pk[c][j0][0], y0 = pk[c][j0 + 1][0];
        unsigned x1 = pk[c][j0][1], y1 = pk[c][j0 + 1][1];
        pl32swap(x0, y0);
        pl32swap(x1, y1);
        u32x4 fv; fv[0] = x0; fv[1] = x1; fv[2] = y0; fv[3] = y1;
        const bf16x8 af = __builtin_bit_cast(bf16x8, fv);
        o0 = MFMA32(af, vfa0[t], o0);
        o1 = MFMA32(af, vfa1[t], o1);
      }
      __builtin_amdgcn_s_setprio(0);
    }

    // ================= half b (kv tile 2*kt2+1) =================
    {
      // V_b issued now; covered by QK^T_b + softmax_b
      bf16x8 vfb0[4], vfb1[4];
#pragma unroll
      for (int t = 0; t < 4; ++t) {
        vfb0[t] = *reinterpret_cast<const bf16x8*>(vpa + 4096 + t * 1024);
        vfb1[t] = *reinterpret_cast<const bf16x8*>(vpa + 4096 + t * 1024 + 256);
      }

      f32x16 s0 = {}, s1 = {};
      __builtin_amdgcn_s_setprio(1);
#pragma unroll
      for (int t = 0; t < 4; ++t) {
        s0 = MFMA32(kfb0[t], qf[t], s0);
        s1 = MFMA32(kfb1[t], qf[t], s1);
      }
      __builtin_amdgcn_s_setprio(0);

      float p0[16], p1[16];
#pragma unroll
      for (int r = 0; r < 16; ++r) p0[r] = EXP2(s0[r]);
#pragma unroll
      for (int r = 0; r < 16; ++r) p1[r] = EXP2(s1[r]);

      float a8[8];
#pragma unroll
      for (int i = 0; i < 8; ++i)
        a8[i] = (p0[2*i] + p0[2*i+1]) + (p1[2*i] + p1[2*i+1]);
      float ts = ((a8[0]+a8[1]) + (a8[2]+a8[3])) + ((a8[4]+a8[5]) + (a8[6]+a8[7]));
      ts += __shfl_xor(ts, 32);
      lrun += ts;

      unsigned pk[2][4][2];
#pragma unroll
      for (int qd = 0; qd < 4; ++qd) {
        pk[0][qd][0] = pack_bf2(p0[4*qd+0], p0[4*qd+1]);
        pk[0][qd][1] = pack_bf2(p0[4*qd+2], p0[4*qd+3]);
        pk[1][qd][0] = pack_bf2(p1[4*qd+0], p1[4*qd+1]);
        pk[1][qd][1] = pack_bf2(p1[4*qd+2], p1[4*qd+3]);
      }

      __builtin_amdgcn_s_setprio(1);
#pragma unroll
      for (int t = 0; t < 4; ++t) {
        const int c = t >> 1, j0 = 2 * (t & 1);
        unsigned x0 = pk[c][j0][0], y0 = pk[c][j0 + 1][0];
        unsigned x1 = pk[c][j0][1], y1 = pk[c][j0 + 1][1];
        pl32swap(x0, y0);
        pl32swap(x1, y1);
        u32x4 fv; fv[0] = x0; fv[1] = x1; fv[2] = y0; fv[3] = y1;
        const bf16x8 af = __builtin_bit_cast(bf16x8, fv);
        o0 = MFMA32(af, vfb0[t], o0);
        o1 = MFMA32(af, vfb1[t], o1);
      }
      __builtin_amdgcn_s_setprio(0);
    }
  }

  // ---- combine halves (R8's proven epilogue; fixed order -> deterministic)
  if (w == 1) {
    if (h == 0) cL[1][q] = lrun;
#pragma unroll
    for (int r = 0; r < 16; ++r) {
      const int crow = (r >> 2) * 8 + 4 * h + (r & 3);
      cO[crow * 64 + q]      = o0[r];
      cO[crow * 64 + 32 + q] = o1[r];
    }
  } else {
    if (h == 0) cL[0][q] = lrun;
  }
  __syncthreads();
  if (w == 0) {
    const int b_ = bh / 12, hd = bh % 12;
#pragma unroll
    for (int r = 0; r < 16; ++r) {
      const int crow = (r >> 2) * 8 + 4 * h + (r & 3);
      const float lt = cL[0][crow] + cL[1][crow];
      const float rl = 1.f / lt;
      const float ot0 = o0[r] + cO[crow * 64 + q];
      const float ot1 = o1[r] + cO[crow * 64 + 32 + q];
      u16* dst = AOb + ((size_t)b_ * 1024 + qt * 32 + crow) * 768 + hd * 64 + q;
      dst[0]  = f2bf(ot0 * rl);
      dst[32] = f2bf(ot1 * rl);
    }
  }
}

// ---------------------------------------------------------------- launch
extern "C" void kernel_launch(void* const* d_in, const int* in_sizes, int n_in,
                              void* d_out, int out_size, void* d_ws, size_t ws_size,
                              hipStream_t stream)
{
  const float* x  = (const float*)d_in[0];
  const float* y  = (const float*)d_in[1];
  const float* wq = (const float*)d_in[2];
  const float* wk = (const float*)d_in[3];
  const float* wv = (const float*)d_in[4];
  const float* wp = (const float*)d_in[5];
  const float* bp = (const float*)d_in[6];
  float* out = (float*)d_out;

  char* ws = (char*)d_ws;
  u16* xb  = (u16*)ws; ws += (size_t)4096 * 768 * 2;
  u16* yb  = (u16*)ws; ws += (size_t)8192 * 768 * 2;
  u16* wqb = (u16*)ws; ws += (size_t)768 * 768 * 2;
  u16* wkb = (u16*)ws; ws += (size_t)768 * 768 * 2;
  u16* wvb = (u16*)ws; ws += (size_t)768 * 768 * 2;
  u16* wpb = (u16*)ws; ws += (size_t)768 * 768 * 2;
  u16* Qa  = (u16*)ws; ws += (size_t)4096 * 768 * 2;
  u16* Ka  = (u16*)ws; ws += (size_t)8192 * 768 * 2;
  u16* Vw  = (u16*)ws; ws += (size_t)8192 * 768 * 2;
  u16* AOb = (u16*)ws; ws += (size_t)4096 * 768 * 2;

  convert_all<<<11520, 256, 0, stream>>>(x, y, wq, wk, wv, wp,
                                         xb, yb, wqb, wkb, wvb, wpb);
  gemm_k<false><<<960, 256, 0, stream>>>(xb, yb, wqb, wkb, wvb,
                                         Qa, Ka, Vw, nullptr, nullptr);
  attn_fwd<<<1536, 128, 0, stream>>>(Qa, Ka, Vw, AOb);
  gemm_k<true><<<192, 256, 0, stream>>>(AOb, nullptr, wpb, nullptr, nullptr,
                                        nullptr, nullptr, nullptr, bp, out);
}

// Round 18
// 101.960 us; speedup vs baseline: 1.0157x; 1.0157x over previous
//
#include <hip/hip_runtime.h>
#include <hip/hip_bf16.h>

typedef unsigned short u16;
typedef __attribute__((ext_vector_type(8))) short bf16x8;
typedef __attribute__((ext_vector_type(4))) float f32x4;
typedef __attribute__((ext_vector_type(16))) float f32x16;
typedef __attribute__((ext_vector_type(4))) unsigned u32x4;

#define MFMA(a, b, c) __builtin_amdgcn_mfma_f32_16x16x32_bf16(a, b, c, 0, 0, 0)
#define MFMA32(a, b, c) __builtin_amdgcn_mfma_f32_32x32x16_bf16(a, b, c, 0, 0, 0)

#define STAGE16(g, l) __builtin_amdgcn_global_load_lds( \
    (const __attribute__((address_space(1))) void*)(g),  \
    (__attribute__((address_space(3))) void*)(l), 16, 0, 0)

#define EXP2(x) __builtin_amdgcn_exp2f(x)

__device__ __forceinline__ u16 f2bf(float f) {
  union { float f; unsigned u; } v; v.f = f;
  return (u16)((v.u + 0x7fffu + ((v.u >> 16) & 1u)) >> 16);
}

// hardware pack: lo -> D[15:0], hi -> D[31:16], RNE
__device__ __forceinline__ unsigned pack_bf2(float lo, float hi) {
  unsigned r;
  asm("v_cvt_pk_bf16_f32 %0, %1, %2" : "=v"(r) : "v"(lo), "v"(hi));
  return r;
}

// swap upper 32 lanes of a with lower 32 lanes of b
__device__ __forceinline__ void pl32swap(unsigned &a, unsigned &b) {
  asm("v_permlane32_swap_b32 %0, %1" : "+v"(a), "+v"(b));
}

// ---------------------------------------------------------------- convert
__global__ __launch_bounds__(256) void convert_all(
    const float* __restrict__ x, const float* __restrict__ y,
    const float* __restrict__ wq, const float* __restrict__ wk,
    const float* __restrict__ wv, const float* __restrict__ wp,
    u16* __restrict__ xb, u16* __restrict__ yb,
    u16* __restrict__ wqb, u16* __restrict__ wkb,
    u16* __restrict__ wvb, u16* __restrict__ wpb)
{
  constexpr int G0 = 4096 * 768 / 4;
  constexpr int G1 = G0 + 8192 * 768 / 4;
  constexpr int GW = 768 * 768 / 4;
  int g = blockIdx.x * 256 + threadIdx.x;
  const float* s; u16* d; int o;
  if      (g < G0)          { s = x;  d = xb;  o = g; }
  else if (g < G1)          { s = y;  d = yb;  o = g - G0; }
  else if (g < G1 + GW)     { s = wq; d = wqb; o = g - G1; }
  else if (g < G1 + 2*GW)   { s = wk; d = wkb; o = g - G1 - GW; }
  else if (g < G1 + 3*GW)   { s = wv; d = wvb; o = g - G1 - 2*GW; }
  else if (g < G1 + 4*GW)   { s = wp; d = wpb; o = g - G1 - 3*GW; }
  else return;
  float4 v = reinterpret_cast<const float4*>(s)[o];
  ushort4 r;
  r.x = f2bf(v.x); r.y = f2bf(v.y); r.z = f2bf(v.z); r.w = f2bf(v.w);
  reinterpret_cast<ushort4*>(d)[o] = r;
}

// ---------------------------------------------------------------- GEMM
// C = A @ W^T (both K-contiguous). 128x128 tile, BK=64, 4 waves (2x2).
// Double-buffered LDS, depth-1 prefetch, one __syncthreads per iter.
// Epilogue writes MFMA-fragment-linearized layouts:
//   Qa[bh][q>>5][t][h2][q&31][8]   (pre-scaled by SCALE*log2e)
//   Ka[bh][kv>>5][t][h2][kv&31][8]
//   Vw[bh][kv>>3][d][kv&7]
template <bool PROJ>
__global__ __launch_bounds__(256) void gemm_k(
    const u16* __restrict__ A0, const u16* __restrict__ A1,
    const u16* __restrict__ W0, const u16* __restrict__ W1,
    const u16* __restrict__ W2,
    u16* __restrict__ Qa, u16* __restrict__ Ka, u16* __restrict__ Vw,
    const float* __restrict__ bias, float* __restrict__ fout)
{
  __shared__ u16 sA[2][128 * 64];
  __shared__ u16 sB[2][128 * 64];

  // XCD-aware bijective swizzle (grid: PROJ ? 192 : 960; both %8 == 0)
  const int nper = PROJ ? 24 : 120;
  int bid = (blockIdx.x & 7) * nper + (blockIdx.x >> 3);

  const u16 *A, *W;
  int mode, mt, nt;
  if (PROJ)           { mode = 3; A = A0; W = W0; mt = bid / 6;        nt = bid % 6; }
  else if (bid < 192) { mode = 0; A = A0; W = W0; mt = bid / 6;        nt = bid % 6; }
  else if (bid < 576) { mode = 1; A = A1; W = W1; mt = (bid-192) / 6;  nt = (bid-192) % 6; }
  else                { mode = 2; A = A1; W = W2; mt = (bid-576) / 6;  nt = (bid-576) % 6; }

  const int tid = threadIdx.x;
  const int w = tid >> 6, l = tid & 63;
  const int wm = w >> 1, wn = w & 1;
  const int g = l >> 4, m = l & 15;

  const int mbase = mt * 128, nbase = nt * 128;

  const int srow = l >> 3;
  const int schunk = ((l & 7) ^ srow) * 8;
  const u16* Ag = A + (size_t)(mbase + srow) * 768 + schunk;
  const u16* Wg = W + (size_t)(nbase + srow) * 768 + schunk;

  f32x4 acc[4][4] = {};

  // prologue: stage tile 0 into buf 0
#pragma unroll
  for (int i = 0; i < 4; ++i) {
    const int ri = (i * 4 + w) * 8;
    STAGE16(Ag + (size_t)ri * 768, (char*)sA[0] + ri * 128);
    STAGE16(Wg + (size_t)ri * 768, (char*)sB[0] + ri * 128);
  }

  for (int kt = 0; kt < 12; ++kt) {
    __syncthreads();   // tile kt DMA landed; buf^1 readers (kt-1) done

    if (kt < 11) {
      const int ko = (kt + 1) * 64;
      const int nb = (kt + 1) & 1;
#pragma unroll
      for (int i = 0; i < 4; ++i) {
        const int ri = (i * 4 + w) * 8;
        STAGE16(Ag + (size_t)ri * 768 + ko, (char*)sA[nb] + ri * 128);
        STAGE16(Wg + (size_t)ri * 768 + ko, (char*)sB[nb] + ri * 128);
      }
    }

    const int cb = kt & 1;
    bf16x8 af[2][4], bfr[2][4];
#pragma unroll
    for (int c = 0; c < 2; ++c)
#pragma unroll
      for (int t = 0; t < 4; ++t) {
        const int ar = wm * 64 + t * 16 + m;
        const int br = wn * 64 + t * 16 + m;
        const int cp = ((c * 4 + g) ^ (l & 7)) * 16;
        af[c][t]  = *reinterpret_cast<const bf16x8*>((const char*)sA[cb] + ar * 128 + cp);
        bfr[c][t] = *reinterpret_cast<const bf16x8*>((const char*)sB[cb] + br * 128 + cp);
      }
#pragma unroll
    for (int c = 0; c < 2; ++c)
#pragma unroll
      for (int mi = 0; mi < 4; ++mi)
#pragma unroll
        for (int ni = 0; ni < 4; ++ni)
          acc[mi][ni] = MFMA(af[c][mi], bfr[c][ni], acc[mi][ni]);
  }

  const float QSCALE = 0.18033688011112042f;  // 0.125 * log2(e)
  const int rowb = mbase + wm * 64 + g * 4;
  const int colb = nbase + wn * 64 + m;
#pragma unroll
  for (int mi = 0; mi < 4; ++mi) {
#pragma unroll
    for (int ni = 0; ni < 4; ++ni) {
      const int col = colb + ni * 16;
      const int h = col >> 6, d = col & 63;
      const int t_ = d >> 4, hh = (d >> 3) & 1, di = d & 7;
      const int fo = t_ * 512 + hh * 256 + di;     // fragment inner offset
      if constexpr (PROJ) {
#pragma unroll
        for (int r = 0; r < 4; ++r) {
          const int row = rowb + mi * 16 + r;
          fout[(size_t)row * 768 + col] = acc[mi][ni][r] + bias[col];
        }
      } else {
        if (mode == 0) {
#pragma unroll
          for (int r = 0; r < 4; ++r) {
            const int row = rowb + mi * 16 + r;
            const int b_ = row >> 10, n = row & 1023;
            Qa[((size_t)(b_ * 12 + h) * 32 + (n >> 5)) * 2048 + fo + (n & 31) * 8] =
                f2bf(acc[mi][ni][r] * QSCALE);
          }
        } else if (mode == 1) {
#pragma unroll
          for (int r = 0; r < 4; ++r) {
            const int row = rowb + mi * 16 + r;
            const int b_ = row >> 11, n = row & 2047;
            Ka[(size_t)(b_ * 12 + h) * 131072 + (n >> 5) * 2048 + fo + (n & 31) * 8] =
                f2bf(acc[mi][ni][r]);
          }
        } else {
          // Vw[bh][n>>3][d][n&7]; 4 regs = tokens n..n+3 (n % 4 == 0)
          const int row = rowb + mi * 16;
          const int b_ = row >> 11, n = row & 2047;
          ushort4 pk;
          pk.x = f2bf(acc[mi][ni][0]); pk.y = f2bf(acc[mi][ni][1]);
          pk.z = f2bf(acc[mi][ni][2]); pk.w = f2bf(acc[mi][ni][3]);
          *reinterpret_cast<ushort4*>(
              Vw + (size_t)(b_ * 12 + h) * 131072 + (n >> 3) * 512 + d * 8 + (n & 7)) = pk;
        }
      }
    }
  }
}

// ---------------------------------------------------------------- attention
// Barrier-free 32x32x16 flash attention (R13's proven body, unchanged),
// regridded for INTRA-CU L1 SHARING of K/V.
// Block = 4 independent waves (256 thr): wave (qw=w&1, half=w>>1) runs
// q-tile 2*qt2+qw over kv half `half`. The two waves with the same half
// sit on the same CU and read IDENTICAL K/V addresses with no barriers
// -> the trailing wave hits the CU's 32KB L1 (16KB/iter working set),
// halving L2 read traffic (786 -> ~400 MB/dispatch). Grid 768 = 48
// heads x 16 q-pairs (head pinned to one XCD). Per-wave work, VGPR,
// and the loop body are byte-identical to R13. Epilogue: half-1 waves
// write O/l partials to cO[qw]/cL[qw]; one barrier; half-0 waves
// combine in fixed order (deterministic) and store.
__global__ __launch_bounds__(256, 3) void attn_fwd(
    const u16* __restrict__ Qa, const u16* __restrict__ Ka,
    const u16* __restrict__ Vw, u16* __restrict__ AOb)
{
  __shared__ float cO[2][32 * 64];
  __shared__ float cL[2][32];

  const int bid = blockIdx.x;
  const int bh = bid % 48, qt2 = bid / 48;  // 48%8==0 -> head pinned to XCD
  const int tid = threadIdx.x;
  const int w = tid >> 6, l = tid & 63;
  const int qw = w & 1, half = w >> 1;
  const int h = l >> 5, q = l & 31;

  // Q B-frags (coalesced 16B): lane holds Q[q0+q][16t+8h+i]
  const int qtile = qt2 * 2 + qw;
  const u16* qb = Qa + (size_t)(bh * 32 + qtile) * 2048 + h * 256 + q * 8;
  bf16x8 qf[4];
#pragma unroll
  for (int t = 0; t < 4; ++t)
    qf[t] = *reinterpret_cast<const bf16x8*>(qb + t * 512);

  // K A-frag base / V B-frag base for this wave's kv half (shared with
  // the partner wave qw^1 on the same CU -> L1 hits)
  const u16* kb = Ka + (size_t)bh * 131072 + (size_t)half * 65536 + h * 256 + q * 8;
  const u16* vb = Vw + (size_t)bh * 131072 + (size_t)half * 65536 + h * 512 + q * 8;

  bf16x8 ones;
#pragma unroll
  for (int i = 0; i < 8; ++i) ones[i] = (short)0x3F80;  // bf16 1.0

  f32x16 o0 = {}, o1 = {}, la = {};

  for (int kt = 0; kt < 16; ++kt) {
    const u16* kp = kb + kt * 4096;
    const u16* vp = vb + kt * 4096;

    // ---- K frags (coalesced; lane = kv row l&31)
    bf16x8 kf0[4], kf1[4];
#pragma unroll
    for (int t = 0; t < 4; ++t) {
      kf0[t] = *reinterpret_cast<const bf16x8*>(kp + t * 512);
      kf1[t] = *reinterpret_cast<const bf16x8*>(kp + 2048 + t * 512);
    }

    // ---- S^T = K @ Q^T
    f32x16 s0 = {}, s1 = {};
    __builtin_amdgcn_s_setprio(1);
#pragma unroll
    for (int t = 0; t < 4; ++t) {
      s0 = MFMA32(kf0[t], qf[t], s0);
      s1 = MFMA32(kf1[t], qf[t], s1);
    }
    __builtin_amdgcn_s_setprio(0);

    // ---- V frags issued now; latency hides under softmax
    bf16x8 vf0[4], vf1[4];
#pragma unroll
    for (int t = 0; t < 4; ++t) {
      vf0[t] = *reinterpret_cast<const bf16x8*>(vp + t * 1024);
      vf1[t] = *reinterpret_cast<const bf16x8*>(vp + t * 1024 + 256);
    }

    // ---- softmax: p = exp2(z); single v_exp_f32 each
    float p0[16], p1[16];
#pragma unroll
    for (int r = 0; r < 16; ++r) p0[r] = EXP2(s0[r]);
#pragma unroll
    for (int r = 0; r < 16; ++r) p1[r] = EXP2(s1[r]);

    // ---- pack P via v_cvt_pk_bf16_f32: quad qd = kv 32c + 8qd + 4h + 0..3
    unsigned pk[2][4][2];
#pragma unroll
    for (int qd = 0; qd < 4; ++qd) {
      pk[0][qd][0] = pack_bf2(p0[4*qd+0], p0[4*qd+1]);
      pk[0][qd][1] = pack_bf2(p0[4*qd+2], p0[4*qd+3]);
      pk[1][qd][0] = pack_bf2(p1[4*qd+0], p1[4*qd+1]);
      pk[1][qd][1] = pack_bf2(p1[4*qd+2], p1[4*qd+3]);
    }

    // ---- PV + l from registers (l on the MFMA pipe)
    __builtin_amdgcn_s_setprio(1);
#pragma unroll
    for (int t = 0; t < 4; ++t) {
      const int c = t >> 1, j0 = 2 * (t & 1);
      unsigned x0 = pk[c][j0][0], y0 = pk[c][j0 + 1][0];
      unsigned x1 = pk[c][j0][1], y1 = pk[c][j0 + 1][1];
      pl32swap(x0, y0);
      pl32swap(x1, y1);
      u32x4 fv; fv[0] = x0; fv[1] = x1; fv[2] = y0; fv[3] = y1;
      const bf16x8 af = __builtin_bit_cast(bf16x8, fv);
      o0 = MFMA32(af, vf0[t], o0);
      o1 = MFMA32(af, vf1[t], o1);
      la = MFMA32(af, ones, la);
    }
    __builtin_amdgcn_s_setprio(0);
  }

  // ---- combine halves per q-tile (single barrier; fixed order)
  if (half == 1) {
#pragma unroll
    for (int r = 0; r < 16; ++r) {
      const int crow = (r >> 2) * 8 + 4 * h + (r & 3);
      cO[qw][crow * 64 + q]      = o0[r];
      cO[qw][crow * 64 + 32 + q] = o1[r];
      if (q == 0) cL[qw][crow] = la[r];
    }
  }
  __syncthreads();
  if (half == 0) {
    const int b_ = bh / 12, hd = bh % 12;
#pragma unroll
    for (int r = 0; r < 16; ++r) {
      const int crow = (r >> 2) * 8 + 4 * h + (r & 3);
      const float lt = la[r] + cL[qw][crow];
      const float rl = 1.f / lt;
      const float ot0 = o0[r] + cO[qw][crow * 64 + q];
      const float ot1 = o1[r] + cO[qw][crow * 64 + 32 + q];
      u16* dst = AOb + ((size_t)b_ * 1024 + qtile * 32 + crow) * 768 + hd * 64 + q;
      dst[0]  = f2bf(ot0 * rl);
      dst[32] = f2bf(ot1 * rl);
    }
  }
}

// ---------------------------------------------------------------- launch
extern "C" void kernel_launch(void* const* d_in, const int* in_sizes, int n_in,
                              void* d_out, int out_size, void* d_ws, size_t ws_size,
                              hipStream_t stream)
{
  const float* x  = (const float*)d_in[0];
  const float* y  = (const float*)d_in[1];
  const float* wq = (const float*)d_in[2];
  const float* wk = (const float*)d_in[3];
  const float* wv = (const float*)d_in[4];
  const float* wp = (const float*)d_in[5];
  const float* bp = (const float*)d_in[6];
  float* out = (float*)d_out;

  char* ws = (char*)d_ws;
  u16* xb  = (u16*)ws; ws += (size_t)4096 * 768 * 2;
  u16* yb  = (u16*)ws; ws += (size_t)8192 * 768 * 2;
  u16* wqb = (u16*)ws; ws += (size_t)768 * 768 * 2;
  u16* wkb = (u16*)ws; ws += (size_t)768 * 768 * 2;
  u16* wvb = (u16*)ws; ws += (size_t)768 * 768 * 2;
  u16* wpb = (u16*)ws; ws += (size_t)768 * 768 * 2;
  u16* Qa  = (u16*)ws; ws += (size_t)4096 * 768 * 2;
  u16* Ka  = (u16*)ws; ws += (size_t)8192 * 768 * 2;
  u16* Vw  = (u16*)ws; ws += (size_t)8192 * 768 * 2;
  u16* AOb = (u16*)ws; ws += (size_t)4096 * 768 * 2;

  convert_all<<<11520, 256, 0, stream>>>(x, y, wq, wk, wv, wp,
                                         xb, yb, wqb, wkb, wvb, wpb);
  gemm_k<false><<<960, 256, 0, stream>>>(xb, yb, wqb, wkb, wvb,
                                         Qa, Ka, Vw, nullptr, nullptr);
  attn_fwd<<<768, 256, 0, stream>>>(Qa, Ka, Vw, AOb);
  gemm_k<true><<<192, 256, 0, stream>>>(AOb, nullptr, wpb, nullptr, nullptr,
                                        nullptr, nullptr, nullptr, bp, out);
}